// Round 14
// baseline (289.668 us; speedup 1.0000x reference)
//
#include <hip/hip_runtime.h>

#define HID 128
#define EPS 1e-5f
#define BSH 8                 // bucket = 256 dst nodes

typedef unsigned short ushort_t;
typedef unsigned int uint_t;
typedef short short8v __attribute__((ext_vector_type(8)));
typedef ushort_t ushort8v __attribute__((ext_vector_type(8)));
typedef float float4v __attribute__((ext_vector_type(4)));

__device__ __forceinline__ ushort_t f2bf_rne(float f) {
    unsigned u = __float_as_uint(f);
    unsigned r = u + 0x7fffu + ((u >> 16) & 1u);
    return (ushort_t)(r >> 16);
}
__device__ __forceinline__ float bf2f_lo(uint_t u) {      // low bf16 of packed pair
    return __uint_as_float(u << 16);
}
__device__ __forceinline__ float bf2f_hi(uint_t u) {      // high bf16 of packed pair
    return __uint_as_float(u & 0xffff0000u);
}

// direct global->LDS DMA, 16B per lane (gfx950)
__device__ __forceinline__ void gload_lds16(const void* g, void* l) {
    __builtin_amdgcn_global_load_lds(
        (const __attribute__((address_space(1))) void*)g,
        (__attribute__((address_space(3))) void*)l, 16, 0, 0);
}

// ---------------- prep: W split (blocks 0..127) + BN coefs (block 128) + zeroing ----------------

__global__ void prep_kernel(const float* __restrict__ W2, const float* __restrict__ W3,
                            ushort_t* __restrict__ Wsw2, ushort_t* __restrict__ Wsw3,
                            const float* __restrict__ b1, const float* __restrict__ g1,
                            const float* __restrict__ be1, const float* __restrict__ m1,
                            const float* __restrict__ v1, float* __restrict__ cA1,
                            float* __restrict__ cC1,
                            const float* __restrict__ b2, const float* __restrict__ g2,
                            const float* __restrict__ be2, const float* __restrict__ m2,
                            const float* __restrict__ v2, float* __restrict__ cA2,
                            float* __restrict__ cC2,
                            const float* __restrict__ b3, const float* __restrict__ g3,
                            const float* __restrict__ be3, const float* __restrict__ m3,
                            const float* __restrict__ v3, float* __restrict__ cA3,
                            float* __restrict__ cC3,
                            int* __restrict__ zbase, int zints) {
    int bb = blockIdx.x;
    if (bb < 128) {
        const float* W = (bb < 64) ? W2 : W3;
        ushort_t* Wsw = (bb < 64) ? Wsw2 : Wsw3;
        int idx = (bb & 63) * 256 + threadIdx.x;
        int k = idx >> 7;        // in
        int o = idx & 127;       // out
        float w = W[idx];        // W[k][o]
        unsigned u = __float_as_uint(w);
        ushort_t hw = (ushort_t)(u >> 16);
        float hf = __uint_as_float(u & 0xffff0000u);
        float lo = w - hf;
        ushort_t lw = (ushort_t)(__float_as_uint(lo) >> 16);
        int chunk = k >> 3, j = k & 7;
        int sidx = o * 128 + ((chunk ^ (o & 7)) << 3) + j;
        Wsw[sidx] = hw;
        Wsw[16384 + sidx] = lw;
    } else if (bb == 128) {
        int c = threadIdx.x;
        if (c < 128) {
            float A1 = g1[c] * rsqrtf(v1[c] + EPS);
            cA1[c] = A1; cC1[c] = (b1[c] - m1[c]) * A1 + be1[c];
            float A2 = g2[c] * rsqrtf(v2[c] + EPS);
            cA2[c] = A2; cC2[c] = (b2[c] - m2[c]) * A2 + be2[c];
            float A3 = g3[c] * rsqrtf(v3[c] + EPS);
            cA3[c] = A3; cC3[c] = (b3[c] - m3[c]) * A3 + be3[c];
        }
    } else {
        int i = (bb - 129) * 256 + threadIdx.x;
        if (i < zints) zbase[i] = 0;
    }
}

// ---------------- bucketed CSR build ----------------

// per-chunk histogram of dst buckets; saves chunkhist for part_kernel reuse.
// Last finishing block performs the 512-wide bucket scan (replaces bktscan_kernel).
__global__ void hist_kernel(const int* __restrict__ col, int E, int chunk,
                            int* __restrict__ bkthist, int* __restrict__ chunkhist, int nbkt,
                            int* __restrict__ done, int* __restrict__ bktbase,
                            int* __restrict__ bktcur) {
    __shared__ int lh[512];
    __shared__ int islast;
    int tid = threadIdx.x;
    for (int i = tid; i < 512; i += 256) lh[i] = 0;
    __syncthreads();
    int base = blockIdx.x * chunk;
    int end = min(base + chunk, E);
    for (int e = base + tid; e < end; e += 256) atomicAdd(&lh[col[e] >> BSH], 1);
    __syncthreads();
    for (int i = tid; i < nbkt; i += 256) {
        int c = lh[i];
        chunkhist[blockIdx.x * 512 + i] = c;
        if (c) atomicAdd(&bkthist[i], c);
    }
    // last-block scan
    __threadfence();
    __syncthreads();
    if (tid == 0) {
        int d = atomicAdd(done, 1);
        islast = (d == (int)gridDim.x - 1);
    }
    __syncthreads();
    if (!islast) return;
    __threadfence();
    __shared__ int a[512];
    __shared__ int s[256];
    a[tid] = (tid < nbkt) ? bkthist[tid] : 0;
    a[tid + 256] = (tid + 256 < nbkt) ? bkthist[tid + 256] : 0;
    __syncthreads();
    s[tid] = a[2 * tid] + a[2 * tid + 1];
    __syncthreads();
    for (int off = 1; off < 256; off <<= 1) {
        int add = (tid >= off) ? s[tid - off] : 0;
        __syncthreads();
        s[tid] += add;
        __syncthreads();
    }
    int pbase = (tid > 0) ? s[tid - 1] : 0;
    int e0 = pbase;
    int e1 = pbase + a[2 * tid];
    int i0 = 2 * tid, i1 = 2 * tid + 1;
    if (i0 <= nbkt) { bktbase[i0] = e0; bktcur[i0] = e0; }
    if (i1 <= nbkt) { bktbase[i1] = e1; bktcur[i1] = e1; }
    if (tid == 255 && 512 <= nbkt) bktbase[512] = s[255];
}

// partition edges using saved chunkhist; single edge sweep, unroll-4 for load ILP
__global__ void part_kernel(const int* __restrict__ row, const int* __restrict__ col,
                            const int* __restrict__ chunkhist, int* __restrict__ bktcur,
                            uint_t* __restrict__ epart, int E, int chunk, int nbkt) {
    __shared__ int cur[512];
    int tid = threadIdx.x;
    int b = blockIdx.x;
    for (int i = tid; i < nbkt; i += 256) {
        int c = chunkhist[b * 512 + i];
        cur[i] = c ? atomicAdd(&bktcur[i], c) : 0;
    }
    __syncthreads();
    int base = b * chunk;
    int end = min(base + chunk, E);
    int e = base + tid;
    for (; e + 768 < end; e += 1024) {
        int d0 = col[e],       d1 = col[e + 256], d2 = col[e + 512], d3 = col[e + 768];
        int r0 = row[e],       r1 = row[e + 256], r2 = row[e + 512], r3 = row[e + 768];
        int p0 = atomicAdd(&cur[d0 >> BSH], 1);
        int p1 = atomicAdd(&cur[d1 >> BSH], 1);
        int p2 = atomicAdd(&cur[d2 >> BSH], 1);
        int p3 = atomicAdd(&cur[d3 >> BSH], 1);
        epart[p0] = (uint_t)r0 | ((uint_t)(d0 & 255) << 24);
        epart[p1] = (uint_t)r1 | ((uint_t)(d1 & 255) << 24);
        epart[p2] = (uint_t)r2 | ((uint_t)(d2 & 255) << 24);
        epart[p3] = (uint_t)r3 | ((uint_t)(d3 & 255) << 24);
    }
    for (; e < end; e += 256) {
        int d = col[e];
        int pos = atomicAdd(&cur[d >> BSH], 1);
        epart[pos] = (uint_t)row[e] | ((uint_t)(d & 255) << 24);
    }
}

// per-bucket degree count -> colptr (bucket-local prefix + bktbase), dinv, gcnt.
__global__ void count_kernel(const uint_t* __restrict__ epart, const int* __restrict__ bktbase,
                             int* __restrict__ colptr, float* __restrict__ dinv,
                             const int* __restrict__ batch, int* __restrict__ gcnt, int N) {
    __shared__ int nc[256];
    __shared__ int sc[256];
    int tid = threadIdx.x;
    int b = blockIdx.x;
    nc[tid] = 0;
    __syncthreads();
    int s = bktbase[b], e2 = bktbase[b + 1];
    for (int i = s + tid; i < e2; i += 256) atomicAdd(&nc[epart[i] >> 24], 1);
    __syncthreads();
    int deg = nc[tid];
    sc[tid] = deg;
    __syncthreads();
    for (int off = 1; off < 256; off <<= 1) {
        int add = (tid >= off) ? sc[tid - off] : 0;
        __syncthreads();
        sc[tid] += add;
        __syncthreads();
    }
    int n = (b << BSH) + tid;
    if (n < N) {
        colptr[n + 1] = s + sc[tid];              // inclusive prefix -> end of node n's span
        dinv[n] = rsqrtf((float)(deg + 1));
        atomicAdd(&gcnt[batch[n]], 1);
    }
    if (b == 0 && tid == 0) colptr[0] = 0;
}

// per-bucket CSR placement of packed {src, dinv[src]}; scattered writes in ~32KB window
__global__ void place_kernel(const uint_t* __restrict__ epart, const int* __restrict__ bktbase,
                             const int* __restrict__ colptr, const float* __restrict__ dinv,
                             int2* __restrict__ swsrcs) {
    __shared__ int nc[256];
    int tid = threadIdx.x;
    int b = blockIdx.x;
    nc[tid] = 0;
    __syncthreads();
    int s = bktbase[b], e2 = bktbase[b + 1];
    for (int i = s + tid; i < e2; i += 256) {
        uint_t pv = epart[i];
        int dl = pv >> 24;
        int d = (b << BSH) + dl;
        int src = (int)(pv & 0xFFFFFFu);
        int pos = atomicAdd(&nc[dl], 1);
        swsrcs[colptr[d] + pos] = make_int2(src, __float_as_int(dinv[src]));
    }
}

// ---------------- layer 1 fused: x aggregation (6ch) + GEMM 6->128 + BN + ReLU -> bf16 h ----
// 8 lanes per node; unroll-8 edge gather with masked final group.

__global__ __launch_bounds__(256) void layer1_kernel(
    const float* __restrict__ x, const float* __restrict__ dinv,
    const int* __restrict__ colptr, const int2* __restrict__ swsrcs,
    const float* __restrict__ W1, const float* __restrict__ cA1,
    const float* __restrict__ cC1, ushort_t* __restrict__ h, int N) {
    __shared__ float W1s[6 * 128];
    __shared__ float cAs[128], cCs[128];
    int tid = threadIdx.x;
    for (int i = tid; i < 768; i += 256) W1s[i] = W1[i];
    if (tid < 128) { cAs[tid] = cA1[tid]; cCs[tid] = cC1[tid]; }
    __syncthreads();

    int g = tid >> 3;        // group (one node each)
    int l = tid & 7;
    int n = blockIdx.x * 32 + g;
    bool valid = n < N;
    int nc = valid ? n : N - 1;          // clamp: keep all lanes active for shfl
    float dn = dinv[nc];
    float acc = (l < 6) ? x[(size_t)nc * 6 + l] * dn * dn : 0.f;
    int s0 = colptr[nc], s1 = colptr[nc + 1];
    int j = s0;
    for (; j + 8 <= s1; j += 8) {            // unmasked main loop, 8 in flight
        int2 sv[8];
#pragma unroll
        for (int u = 0; u < 8; u++) sv[u] = swsrcs[j + u];
        float xv[8];
#pragma unroll
        for (int u = 0; u < 8; u++)
            xv[u] = (l < 6) ? x[(size_t)sv[u].x * 6 + l] : 0.f;
#pragma unroll
        for (int u = 0; u < 8; u++)
            acc += xv[u] * (__int_as_float(sv[u].y) * dn);
    }
    if (j < s1) {                             // single masked final group
        int2 sv[8];
#pragma unroll
        for (int u = 0; u < 8; u++) {
            int idx = (j + u < s1) ? (j + u) : (s1 - 1);
            sv[u] = swsrcs[idx];
        }
        float xv[8];
#pragma unroll
        for (int u = 0; u < 8; u++)
            xv[u] = (l < 6) ? x[(size_t)sv[u].x * 6 + l] : 0.f;
#pragma unroll
        for (int u = 0; u < 8; u++) {
            float w = (j + u < s1) ? __int_as_float(sv[u].y) * dn : 0.f;
            acc += xv[u] * w;
        }
    }
    // broadcast the 6 agg values within the 8-lane group
    int base = (tid & 63) & ~7;
    float a0 = __shfl(acc, base + 0);
    float a1 = __shfl(acc, base + 1);
    float a2 = __shfl(acc, base + 2);
    float a3 = __shfl(acc, base + 3);
    float a4 = __shfl(acc, base + 4);
    float a5 = __shfl(acc, base + 5);
    if (valid) {
#pragma unroll
        for (int half = 0; half < 2; half++) {
            ushort8v o;
#pragma unroll
            for (int cc = 0; cc < 8; cc++) {
                int c = l * 16 + half * 8 + cc;
                float v = a0 * W1s[c] + a1 * W1s[128 + c] + a2 * W1s[256 + c]
                        + a3 * W1s[384 + c] + a4 * W1s[512 + c] + a5 * W1s[640 + c];
                v = v * cAs[c] + cCs[c];
                o[cc] = f2bf_rne(v > 0.f ? v : 0.f);
            }
            *(ushort8v*)&h[(size_t)n * HID + l * 16 + half * 8] = o;
        }
    }
}

// ---------------- 128-wide aggregation: one wave per node, scalarized metadata ----------------

__global__ __launch_bounds__(256) void agg_kernel(
    const ushort_t* __restrict__ h, const float* __restrict__ dinv,
    const int* __restrict__ colptr, const int2* __restrict__ swsrcs,
    ushort_t* __restrict__ aggb, int N) {
    int lane = threadIdx.x & 63;
    int n = __builtin_amdgcn_readfirstlane(blockIdx.x * 4 + (threadIdx.x >> 6));
    if (n >= N) return;
    float dn = dinv[n];
    const uint_t* hv = (const uint_t*)h;  // row = 64 uints (128 bf16)
    float ax, ay;
    {
        uint_t hs = hv[(size_t)n * 64 + lane];
        float sw = dn * dn;
        ax = bf2f_lo(hs) * sw;
        ay = bf2f_hi(hs) * sw;
    }
    int s0 = colptr[n], s1 = colptr[n + 1];
    int j = s0;
    for (; j + 8 <= s1; j += 8) {                 // full-rate unmasked main loop
        int2 sv[8];
#pragma unroll
        for (int u = 0; u < 8; u++) sv[u] = swsrcs[j + u];
        uint_t hh[8];
#pragma unroll
        for (int u = 0; u < 8; u++) hh[u] = hv[(size_t)sv[u].x * 64 + lane];
#pragma unroll
        for (int u = 0; u < 8; u++) {
            float w = __int_as_float(sv[u].y) * dn;
            ax += bf2f_lo(hh[u]) * w;
            ay += bf2f_hi(hh[u]) * w;
        }
    }
    if (j < s1) {                                  // single masked group for remainder
        int2 sv[8];
#pragma unroll
        for (int u = 0; u < 8; u++) {
            int idx = (j + u < s1) ? (j + u) : (s1 - 1);
            sv[u] = swsrcs[idx];
        }
        uint_t hh[8];
#pragma unroll
        for (int u = 0; u < 8; u++) hh[u] = hv[(size_t)sv[u].x * 64 + lane];
#pragma unroll
        for (int u = 0; u < 8; u++) {
            float w = (j + u < s1) ? __int_as_float(sv[u].y) * dn : 0.f;
            ax += bf2f_lo(hh[u]) * w;
            ay += bf2f_hi(hh[u]) * w;
        }
    }
    uint_t o = (uint_t)f2bf_rne(ax) | ((uint_t)f2bf_rne(ay) << 16);
    ((uint_t*)aggb)[(size_t)n * 64 + lane] = o;
}

// ---------------- MFMA GEMM: bf16 A x (Wh+Wl) + BN + ReLU (+ fused pool) ----------------

template <bool POOL>
__global__ __launch_bounds__(256, 2) void gemm_mfma_kernel(
    const ushort_t* __restrict__ aggb,    // [N][128] bf16
    const ushort_t* __restrict__ Wsw,     // swizzled hi||lo, 64 KB
    const float* __restrict__ cA,         // [128] BN scale
    const float* __restrict__ cC,         // [128] BN shift
    ushort_t* __restrict__ out_h,         // non-pool: bf16 h out
    float* __restrict__ out_pool,         // pool: f32 accum out (workspace)
    const int* __restrict__ batch, int N) {
    __shared__ unsigned smu[16384];       // 64 KB: W(hi|lo) during K-loop, f32 tile in epilogue
    ushort_t* Wh = (ushort_t*)smu;
    ushort_t* Wl = (ushort_t*)smu + 16384;
    float* At = (float*)smu;

    int tid  = threadIdx.x;
    int wid  = tid >> 6;           // wave 0..3
    int lane = tid & 63;
    int l15  = lane & 15;
    int lg   = lane >> 4;          // 0..3

    int nbase = blockIdx.x * 128;
    int rbase = nbase + wid * 32;
    int r0c = min(rbase + l15, N - 1);
    int r1c = min(rbase + 16 + l15, N - 1);

    // stage W into LDS via direct global->LDS DMA (linear layout, pre-swizzled in global)
    {
        const char* g = (const char*)Wsw;
        char* l = (char*)smu;
        int wbase = (tid & ~63) << 4;      // wave-uniform LDS base within each 4KB chunk
#pragma unroll
        for (int i = 0; i < 16; i++) {
            gload_lds16(g + i * 4096 + tid * 16, l + i * 4096 + wbase);
        }
    }

    // BN coefs for this lane's 8 output channels (overlaps with DMA)
    float kA[8], kC[8];
#pragma unroll
    for (int cb = 0; cb < 8; cb++) {
        int n = cb * 16 + l15;
        kA[cb] = cA[n];
        kC[cb] = cC[n];
    }
    __syncthreads();

    float4v acc[2][8];
#pragma unroll
    for (int h = 0; h < 2; h++)
#pragma unroll
        for (int cb = 0; cb < 8; cb++) acc[h][cb] = (float4v){0.f, 0.f, 0.f, 0.f};

#pragma unroll
    for (int kk = 0; kk < 4; kk++) {
        int ko = kk * 32 + lg * 8;             // 8 consecutive k per lane
        short8v Ah0 = *(const short8v*)(aggb + (size_t)r0c * HID + ko);
        short8v Ah1 = *(const short8v*)(aggb + (size_t)r1c * HID + ko);
        int chunk = kk * 4 + lg;
#pragma unroll
        for (int cb = 0; cb < 8; cb++) {
            int n = cb * 16 + l15;
            int sidx = n * 128 + ((chunk ^ (n & 7)) << 3);
            short8v bh = *(const short8v*)(Wh + sidx);
            short8v bl = *(const short8v*)(Wl + sidx);
            acc[0][cb] = __builtin_amdgcn_mfma_f32_16x16x32_bf16(Ah0, bh, acc[0][cb], 0, 0, 0);
            acc[1][cb] = __builtin_amdgcn_mfma_f32_16x16x32_bf16(Ah1, bh, acc[1][cb], 0, 0, 0);
            acc[0][cb] = __builtin_amdgcn_mfma_f32_16x16x32_bf16(Ah0, bl, acc[0][cb], 0, 0, 0);
            acc[1][cb] = __builtin_amdgcn_mfma_f32_16x16x32_bf16(Ah1, bl, acc[1][cb], 0, 0, 0);
        }
    }

    __syncthreads();   // all waves done reading W; reuse LDS as f32 tile

    // BN + ReLU, write acc into LDS tile [128][128] with col swizzle
#pragma unroll
    for (int h = 0; h < 2; h++) {
#pragma unroll
        for (int r = 0; r < 4; r++) {
            int lr = wid * 32 + h * 16 + lg * 4 + r;
            int swz = ((lr >> 2) & 3) << 2;
#pragma unroll
            for (int cb = 0; cb < 8; cb++) {
                int c = cb * 16 + l15;
                float val = fmaxf(acc[h][cb][r] * kA[cb] + kC[cb], 0.f);
                if (POOL && (nbase + lr) >= N) val = 0.f;
                At[lr * 128 + (c ^ swz)] = val;
            }
        }
    }
    __syncthreads();

    if (!POOL) {
        // coalesced bf16 row writes: 16 threads x 8ch cover a 256B row
        int c8 = tid & 15;           // 8-channel chunk
        int rb = tid >> 4;           // 16 rows per pass
#pragma unroll
        for (int i = 0; i < 8; i++) {
            int r = rb + i * 16;
            int gr = nbase + r;
            if (gr < N) {
                int swz = ((r >> 2) & 3) << 2;
                float4 va = *(float4*)&At[r * 128 + ((c8 * 8) ^ swz)];
                float4 vb = *(float4*)&At[r * 128 + ((c8 * 8 + 4) ^ swz)];
                ushort8v o;
                o[0] = f2bf_rne(va.x); o[1] = f2bf_rne(va.y);
                o[2] = f2bf_rne(va.z); o[3] = f2bf_rne(va.w);
                o[4] = f2bf_rne(vb.x); o[5] = f2bf_rne(vb.y);
                o[6] = f2bf_rne(vb.z); o[7] = f2bf_rne(vb.w);
                *(ushort8v*)&out_h[(size_t)gr * HID + c8 * 8] = o;
            }
        }
    } else {
        // segmented pool reduction: batch is sorted, few segments per block
        int c  = tid & 127;
        int rh = tid >> 7;          // 0..1, rows rh*64 .. rh*64+63
        int r0 = rh * 64;
        int cg = batch[min(nbase + r0, N - 1)];
        float racc = 0.f;
        for (int r = r0; r < r0 + 64; r++) {
            int gr = min(nbase + r, N - 1);
            int g = batch[gr];
            float vv = At[r * 128 + (c ^ (((r >> 2) & 3) << 2))];
            if (g != cg) {
                atomicAdd(&out_pool[(size_t)cg * HID + c], racc);
                racc = 0.f;
                cg = g;
            }
            racc += vv;
        }
        atomicAdd(&out_pool[(size_t)cg * HID + c], racc);
    }
}

// ---------------- pooling finalize: poolbuf / count -> d_out (writes every element) ----------------

__global__ void finalize_kernel(const float* __restrict__ poolbuf, float* __restrict__ out,
                                const int* __restrict__ gcnt, int total) {
    int i = blockIdx.x * blockDim.x + threadIdx.x;
    if (i < total) {
        int gidx = i >> 7;
        out[i] = poolbuf[i] / fmaxf((float)gcnt[gidx], 1.f);
    }
}

// ---------------- launch ----------------

extern "C" void kernel_launch(void* const* d_in, const int* in_sizes, int n_in,
                              void* d_out, int out_size, void* d_ws, size_t ws_size,
                              hipStream_t stream) {
    const float* x   = (const float*)d_in[0];
    const int*  ei   = (const int*)d_in[1];
    const int*  batch= (const int*)d_in[3];
    const float* W1  = (const float*)d_in[4];
    const float* b1  = (const float*)d_in[5];
    const float* W2  = (const float*)d_in[6];
    const float* b2  = (const float*)d_in[7];
    const float* W3  = (const float*)d_in[8];
    const float* b3  = (const float*)d_in[9];
    const float* g1  = (const float*)d_in[10];
    const float* be1 = (const float*)d_in[11];
    const float* m1  = (const float*)d_in[12];
    const float* v1  = (const float*)d_in[13];
    const float* g2  = (const float*)d_in[14];
    const float* be2 = (const float*)d_in[15];
    const float* m2  = (const float*)d_in[16];
    const float* v2  = (const float*)d_in[17];
    const float* g3  = (const float*)d_in[18];
    const float* be3 = (const float*)d_in[19];
    const float* m3  = (const float*)d_in[20];
    const float* v3  = (const float*)d_in[21];

    const int N  = in_sizes[0] / 6;
    const int E  = in_sizes[1] / 2;
    const int NG = out_size / HID;
    const int* row = ei;
    const int* col = ei + E;
    const int NBKT = (N + 255) >> BSH;        // 391 for N=100000 (<=512 supported)

    char* wp = (char*)d_ws;
    auto alloc = [&](size_t bytes) -> void* {
        void* p = (void*)wp;
        wp += (bytes + 255) & ~(size_t)255;
        return p;
    };
    // bkthist, done, gcnt, poolbuf adjacent -> single zero span handled by prep_kernel
    int*   bkthist = (int*)alloc((size_t)(NBKT + 1) * 4);
    int*   done    = (int*)alloc(256);
    int*   gcnt    = (int*)alloc((size_t)NG * 4);
    float* poolbuf = (float*)alloc((size_t)NG * HID * 4);
    const int zints = (int)(((char*)poolbuf + (size_t)NG * HID * 4 - (char*)bkthist) / 4);
    float* dinv    = (float*)alloc((size_t)N * 4);
    int*   colptr  = (int*)alloc(((size_t)N + 1) * 4);
    int*   bktbase = (int*)alloc((size_t)520 * 4);
    int*   bktcur  = (int*)alloc((size_t)520 * 4);
    int*   chunkhist = (int*)alloc((size_t)256 * 512 * 4);
    uint_t* epart  = (uint_t*)alloc((size_t)E * 4);
    int2*  swsrcs  = (int2*)alloc((size_t)E * 8);
    ushort_t* aggb = (ushort_t*)alloc((size_t)N * HID * 2);
    ushort_t* h    = (ushort_t*)alloc((size_t)N * HID * 2);
    ushort_t* Wsw2 = (ushort_t*)alloc((size_t)2 * HID * HID * 2);
    ushort_t* Wsw3 = (ushort_t*)alloc((size_t)2 * HID * HID * 2);
    float* cA1 = (float*)alloc(HID * 4);
    float* cC1 = (float*)alloc(HID * 4);
    float* cA2 = (float*)alloc(HID * 4);
    float* cC2 = (float*)alloc(HID * 4);
    float* cA3 = (float*)alloc(HID * 4);
    float* cC3 = (float*)alloc(HID * 4);
    float* outf   = (float*)d_out;

    const int B = 256;
    const int ZB = (zints + 255) / 256;
    prep_kernel<<<129 + ZB, B, 0, stream>>>(W2, W3, Wsw2, Wsw3,
                                            b1, g1, be1, m1, v1, cA1, cC1,
                                            b2, g2, be2, m2, v2, cA2, cC2,
                                            b3, g3, be3, m3, v3, cA3, cC3,
                                            bkthist, zints);

    // bucketed CSR build (hist absorbs the bucket scan via last-block)
    const int PB = 256;
    const int pchunk = (E + PB - 1) / PB;
    hist_kernel<<<PB, B, 0, stream>>>(col, E, pchunk, bkthist, chunkhist, NBKT,
                                      done, bktbase, bktcur);
    part_kernel<<<PB, B, 0, stream>>>(row, col, chunkhist, bktcur, epart, E, pchunk, NBKT);
    count_kernel<<<NBKT, B, 0, stream>>>(epart, bktbase, colptr, dinv, batch, gcnt, N);
    place_kernel<<<NBKT, B, 0, stream>>>(epart, bktbase, colptr, dinv, swsrcs);

    // layer 1 (fused aggregate-x + GEMM1 + BN + ReLU)
    layer1_kernel<<<(N + 31) / 32, B, 0, stream>>>(x, dinv, colptr, swsrcs,
                                                   W1, cA1, cC1, h, N);

    const int NBLK = (N + 127) / 128;
    // layer 2
    agg_kernel<<<(N + 3) / 4, B, 0, stream>>>(h, dinv, colptr, swsrcs, aggb, N);
    gemm_mfma_kernel<false><<<NBLK, 256, 0, stream>>>(aggb, Wsw2, cA2, cC2, h, nullptr, nullptr, N);

    // layer 3 (+ fused mean-pool accumulate into poolbuf)
    agg_kernel<<<(N + 3) / 4, B, 0, stream>>>(h, dinv, colptr, swsrcs, aggb, N);
    gemm_mfma_kernel<true><<<NBLK, 256, 0, stream>>>(aggb, Wsw3, cA3, cC3, nullptr, poolbuf, batch, N);

    finalize_kernel<<<(NG * HID + B - 1) / B, B, 0, stream>>>(poolbuf, outf, gcnt, NG * HID);
}

// Round 15
// 283.768 us; speedup vs baseline: 1.0208x; 1.0208x over previous
//
#include <hip/hip_runtime.h>

#define HID 128
#define EPS 1e-5f
#define BSH 8                 // bucket = 256 dst nodes

typedef unsigned short ushort_t;
typedef unsigned int uint_t;
typedef short short8v __attribute__((ext_vector_type(8)));
typedef ushort_t ushort8v __attribute__((ext_vector_type(8)));
typedef float float4v __attribute__((ext_vector_type(4)));

__device__ __forceinline__ ushort_t f2bf_rne(float f) {
    unsigned u = __float_as_uint(f);
    unsigned r = u + 0x7fffu + ((u >> 16) & 1u);
    return (ushort_t)(r >> 16);
}
__device__ __forceinline__ float bf2f_lo(uint_t u) {      // low bf16 of packed pair
    return __uint_as_float(u << 16);
}
__device__ __forceinline__ float bf2f_hi(uint_t u) {      // high bf16 of packed pair
    return __uint_as_float(u & 0xffff0000u);
}

// direct global->LDS DMA, 16B per lane (gfx950)
__device__ __forceinline__ void gload_lds16(const void* g, void* l) {
    __builtin_amdgcn_global_load_lds(
        (const __attribute__((address_space(1))) void*)g,
        (__attribute__((address_space(3))) void*)l, 16, 0, 0);
}

// ---------------- prep: W split (blocks 0..127) + BN coefs (block 128) + zeroing ----------------

__global__ void prep_kernel(const float* __restrict__ W2, const float* __restrict__ W3,
                            ushort_t* __restrict__ Wsw2, ushort_t* __restrict__ Wsw3,
                            const float* __restrict__ b1, const float* __restrict__ g1,
                            const float* __restrict__ be1, const float* __restrict__ m1,
                            const float* __restrict__ v1, float* __restrict__ cA1,
                            float* __restrict__ cC1,
                            const float* __restrict__ b2, const float* __restrict__ g2,
                            const float* __restrict__ be2, const float* __restrict__ m2,
                            const float* __restrict__ v2, float* __restrict__ cA2,
                            float* __restrict__ cC2,
                            const float* __restrict__ b3, const float* __restrict__ g3,
                            const float* __restrict__ be3, const float* __restrict__ m3,
                            const float* __restrict__ v3, float* __restrict__ cA3,
                            float* __restrict__ cC3,
                            int* __restrict__ zbase, int zints) {
    int bb = blockIdx.x;
    if (bb < 128) {
        const float* W = (bb < 64) ? W2 : W3;
        ushort_t* Wsw = (bb < 64) ? Wsw2 : Wsw3;
        int idx = (bb & 63) * 256 + threadIdx.x;
        int k = idx >> 7;        // in
        int o = idx & 127;       // out
        float w = W[idx];        // W[k][o]
        unsigned u = __float_as_uint(w);
        ushort_t hw = (ushort_t)(u >> 16);
        float hf = __uint_as_float(u & 0xffff0000u);
        float lo = w - hf;
        ushort_t lw = (ushort_t)(__float_as_uint(lo) >> 16);
        int chunk = k >> 3, j = k & 7;
        int sidx = o * 128 + ((chunk ^ (o & 7)) << 3) + j;
        Wsw[sidx] = hw;
        Wsw[16384 + sidx] = lw;
    } else if (bb == 128) {
        int c = threadIdx.x;
        if (c < 128) {
            float A1 = g1[c] * rsqrtf(v1[c] + EPS);
            cA1[c] = A1; cC1[c] = (b1[c] - m1[c]) * A1 + be1[c];
            float A2 = g2[c] * rsqrtf(v2[c] + EPS);
            cA2[c] = A2; cC2[c] = (b2[c] - m2[c]) * A2 + be2[c];
            float A3 = g3[c] * rsqrtf(v3[c] + EPS);
            cA3[c] = A3; cC3[c] = (b3[c] - m3[c]) * A3 + be3[c];
        }
    } else {
        int i = (bb - 129) * 256 + threadIdx.x;
        if (i < zints) zbase[i] = 0;
    }
}

// ---------------- bucketed CSR build ----------------

// per-chunk histogram of dst buckets; saves chunkhist for part_kernel reuse
__global__ void hist_kernel(const int* __restrict__ col, int E, int chunk,
                            int* __restrict__ bkthist, int* __restrict__ chunkhist, int nbkt) {
    __shared__ int lh[512];
    int tid = threadIdx.x;
    for (int i = tid; i < 512; i += 256) lh[i] = 0;
    __syncthreads();
    int base = blockIdx.x * chunk;
    int end = min(base + chunk, E);
    for (int e = base + tid; e < end; e += 256) atomicAdd(&lh[col[e] >> BSH], 1);
    __syncthreads();
    for (int i = tid; i < nbkt; i += 256) {
        int c = lh[i];
        chunkhist[blockIdx.x * 512 + i] = c;
        if (c) atomicAdd(&bkthist[i], c);
    }
}

// single-block scan of bucket counts -> bktbase[nbkt+1], bktcur copy
__global__ void bktscan_kernel(const int* __restrict__ bkthist, int* __restrict__ bktbase,
                               int* __restrict__ bktcur, int nbkt) {
    __shared__ int sm[512];
    int t = threadIdx.x;
    int v = (t < nbkt) ? bkthist[t] : 0;
    sm[t] = v;
    __syncthreads();
    for (int off = 1; off < 512; off <<= 1) {
        int add = (t >= off) ? sm[t - off] : 0;
        __syncthreads();
        sm[t] += add;
        __syncthreads();
    }
    if (t < nbkt) {
        int ex = sm[t] - v;
        bktbase[t] = ex;
        bktcur[t] = ex;
    }
    if (t == 511) bktbase[nbkt] = sm[511];
}

// partition edges using saved chunkhist; single edge sweep, no global cnt atomics
__global__ void part_kernel(const int* __restrict__ row, const int* __restrict__ col,
                            const int* __restrict__ chunkhist, int* __restrict__ bktcur,
                            uint_t* __restrict__ epart, int E, int chunk, int nbkt) {
    __shared__ int cur[512];
    int tid = threadIdx.x;
    int b = blockIdx.x;
    for (int i = tid; i < nbkt; i += 256) {
        int c = chunkhist[b * 512 + i];
        cur[i] = c ? atomicAdd(&bktcur[i], c) : 0;
    }
    __syncthreads();
    int base = b * chunk;
    int end = min(base + chunk, E);
    for (int e = base + tid; e < end; e += 256) {
        int d = col[e];
        int pos = atomicAdd(&cur[d >> BSH], 1);
        epart[pos] = (uint_t)row[e] | ((uint_t)(d & 255) << 24);
    }
}

// per-bucket degree count -> colptr (bucket-local prefix + bktbase), dinv, gcnt.
__global__ void count_kernel(const uint_t* __restrict__ epart, const int* __restrict__ bktbase,
                             int* __restrict__ colptr, float* __restrict__ dinv,
                             const int* __restrict__ batch, int* __restrict__ gcnt, int N) {
    __shared__ int nc[256];
    __shared__ int sc[256];
    int tid = threadIdx.x;
    int b = blockIdx.x;
    nc[tid] = 0;
    __syncthreads();
    int s = bktbase[b], e2 = bktbase[b + 1];
    for (int i = s + tid; i < e2; i += 256) atomicAdd(&nc[epart[i] >> 24], 1);
    __syncthreads();
    int deg = nc[tid];
    sc[tid] = deg;
    __syncthreads();
    for (int off = 1; off < 256; off <<= 1) {
        int add = (tid >= off) ? sc[tid - off] : 0;
        __syncthreads();
        sc[tid] += add;
        __syncthreads();
    }
    int n = (b << BSH) + tid;
    if (n < N) {
        colptr[n + 1] = s + sc[tid];              // inclusive prefix -> end of node n's span
        dinv[n] = rsqrtf((float)(deg + 1));
        atomicAdd(&gcnt[batch[n]], 1);
    }
    if (b == 0 && tid == 0) colptr[0] = 0;
}

// per-bucket CSR placement of packed {src, dinv[src]}; scattered writes in ~32KB window
__global__ void place_kernel(const uint_t* __restrict__ epart, const int* __restrict__ bktbase,
                             const int* __restrict__ colptr, const float* __restrict__ dinv,
                             int2* __restrict__ swsrcs) {
    __shared__ int nc[256];
    int tid = threadIdx.x;
    int b = blockIdx.x;
    nc[tid] = 0;
    __syncthreads();
    int s = bktbase[b], e2 = bktbase[b + 1];
    for (int i = s + tid; i < e2; i += 256) {
        uint_t pv = epart[i];
        int dl = pv >> 24;
        int d = (b << BSH) + dl;
        int src = (int)(pv & 0xFFFFFFu);
        int pos = atomicAdd(&nc[dl], 1);
        swsrcs[colptr[d] + pos] = make_int2(src, __float_as_int(dinv[src]));
    }
}

// ---------------- layer 1 fused: x aggregation (6ch) + GEMM 6->128 + BN + ReLU -> bf16 h ----

__global__ __launch_bounds__(256) void layer1_kernel(
    const float* __restrict__ x, const float* __restrict__ dinv,
    const int* __restrict__ colptr, const int2* __restrict__ swsrcs,
    const float* __restrict__ W1, const float* __restrict__ cA1,
    const float* __restrict__ cC1, ushort_t* __restrict__ h, int N) {
    __shared__ float W1s[6 * 128];
    __shared__ float cAs[128], cCs[128];
    int tid = threadIdx.x;
    for (int i = tid; i < 768; i += 256) W1s[i] = W1[i];
    if (tid < 128) { cAs[tid] = cA1[tid]; cCs[tid] = cC1[tid]; }
    __syncthreads();

    int g = tid >> 3;        // group (one node each)
    int l = tid & 7;
    int n = blockIdx.x * 32 + g;
    bool valid = n < N;
    int nc = valid ? n : N - 1;          // clamp: keep all lanes active for shfl
    float dn = dinv[nc];
    float acc = (l < 6) ? x[(size_t)nc * 6 + l] * dn * dn : 0.f;
    int s0 = colptr[nc], s1 = colptr[nc + 1];
    for (int j = s0; j < s1; j += 4) {
        int2 sv[4];
#pragma unroll
        for (int u = 0; u < 4; u++) {
            int idx = (j + u < s1) ? (j + u) : (s1 - 1);
            sv[u] = swsrcs[idx];
        }
        float xv[4];
#pragma unroll
        for (int u = 0; u < 4; u++)
            xv[u] = (l < 6) ? x[(size_t)sv[u].x * 6 + l] : 0.f;
#pragma unroll
        for (int u = 0; u < 4; u++) {
            float w = (j + u < s1) ? __int_as_float(sv[u].y) * dn : 0.f;
            acc += xv[u] * w;
        }
    }
    // broadcast the 6 agg values within the 8-lane group
    int base = (tid & 63) & ~7;
    float a0 = __shfl(acc, base + 0);
    float a1 = __shfl(acc, base + 1);
    float a2 = __shfl(acc, base + 2);
    float a3 = __shfl(acc, base + 3);
    float a4 = __shfl(acc, base + 4);
    float a5 = __shfl(acc, base + 5);
    if (valid) {
#pragma unroll
        for (int half = 0; half < 2; half++) {
            ushort8v o;
#pragma unroll
            for (int cc = 0; cc < 8; cc++) {
                int c = l * 16 + half * 8 + cc;
                float v = a0 * W1s[c] + a1 * W1s[128 + c] + a2 * W1s[256 + c]
                        + a3 * W1s[384 + c] + a4 * W1s[512 + c] + a5 * W1s[640 + c];
                v = v * cAs[c] + cCs[c];
                o[cc] = f2bf_rne(v > 0.f ? v : 0.f);
            }
            *(ushort8v*)&h[(size_t)n * HID + l * 16 + half * 8] = o;
        }
    }
}

// ---------------- 128-wide aggregation: one wave per node, scalarized metadata ----------------

__global__ __launch_bounds__(256) void agg_kernel(
    const ushort_t* __restrict__ h, const float* __restrict__ dinv,
    const int* __restrict__ colptr, const int2* __restrict__ swsrcs,
    ushort_t* __restrict__ aggb, int N) {
    int lane = threadIdx.x & 63;
    int n = __builtin_amdgcn_readfirstlane(blockIdx.x * 4 + (threadIdx.x >> 6));
    if (n >= N) return;
    float dn = dinv[n];
    const uint_t* hv = (const uint_t*)h;  // row = 64 uints (128 bf16)
    float ax, ay;
    {
        uint_t hs = hv[(size_t)n * 64 + lane];
        float sw = dn * dn;
        ax = bf2f_lo(hs) * sw;
        ay = bf2f_hi(hs) * sw;
    }
    int s0 = colptr[n], s1 = colptr[n + 1];
    int j = s0;
    for (; j + 8 <= s1; j += 8) {                 // full-rate unmasked main loop
        int2 sv[8];
#pragma unroll
        for (int u = 0; u < 8; u++) sv[u] = swsrcs[j + u];
        uint_t hh[8];
#pragma unroll
        for (int u = 0; u < 8; u++) hh[u] = hv[(size_t)sv[u].x * 64 + lane];
#pragma unroll
        for (int u = 0; u < 8; u++) {
            float w = __int_as_float(sv[u].y) * dn;
            ax += bf2f_lo(hh[u]) * w;
            ay += bf2f_hi(hh[u]) * w;
        }
    }
    if (j < s1) {                                  // single masked group for remainder
        int2 sv[8];
#pragma unroll
        for (int u = 0; u < 8; u++) {
            int idx = (j + u < s1) ? (j + u) : (s1 - 1);
            sv[u] = swsrcs[idx];
        }
        uint_t hh[8];
#pragma unroll
        for (int u = 0; u < 8; u++) hh[u] = hv[(size_t)sv[u].x * 64 + lane];
#pragma unroll
        for (int u = 0; u < 8; u++) {
            float w = (j + u < s1) ? __int_as_float(sv[u].y) * dn : 0.f;
            ax += bf2f_lo(hh[u]) * w;
            ay += bf2f_hi(hh[u]) * w;
        }
    }
    uint_t o = (uint_t)f2bf_rne(ax) | ((uint_t)f2bf_rne(ay) << 16);
    ((uint_t*)aggb)[(size_t)n * 64 + lane] = o;
}

// ---------------- MFMA GEMM: 256 rows/block, bf16 A x (Wh+Wl) + BN + ReLU (+ fused pool) ----
// 64KB W staging amortized over 2x MFMA work; epilogue = two 128-row LDS passes.

template <bool POOL>
__global__ __launch_bounds__(256, 2) void gemm_mfma_kernel(
    const ushort_t* __restrict__ aggb,    // [N][128] bf16
    const ushort_t* __restrict__ Wsw,     // swizzled hi||lo, 64 KB
    const float* __restrict__ cA,         // [128] BN scale
    const float* __restrict__ cC,         // [128] BN shift
    ushort_t* __restrict__ out_h,         // non-pool: bf16 h out
    float* __restrict__ out_pool,         // pool: f32 accum out (workspace)
    const int* __restrict__ batch, int N) {
    __shared__ unsigned smu[16384];       // 64 KB: W(hi|lo) during K-loop, f32 tile in epilogue
    ushort_t* Wh = (ushort_t*)smu;
    ushort_t* Wl = (ushort_t*)smu + 16384;
    float* At = (float*)smu;

    int tid  = threadIdx.x;
    int wid  = tid >> 6;           // wave 0..3
    int lane = tid & 63;
    int l15  = lane & 15;
    int lg   = lane >> 4;          // 0..3

    int nbase = blockIdx.x * 256;
    int rbase = nbase + wid * 64;  // this wave: 64 rows (4 halves of 16)
    int rc[4];
#pragma unroll
    for (int hh = 0; hh < 4; hh++) rc[hh] = min(rbase + hh * 16 + l15, N - 1);

    // stage W into LDS via direct global->LDS DMA (linear layout, pre-swizzled in global)
    {
        const char* g = (const char*)Wsw;
        char* l = (char*)smu;
        int wbase = (tid & ~63) << 4;      // wave-uniform LDS base within each 4KB chunk
#pragma unroll
        for (int i = 0; i < 16; i++) {
            gload_lds16(g + i * 4096 + tid * 16, l + i * 4096 + wbase);
        }
    }

    // BN coefs for this lane's 8 output channels (overlaps with DMA)
    float kA[8], kC[8];
#pragma unroll
    for (int cb = 0; cb < 8; cb++) {
        int n = cb * 16 + l15;
        kA[cb] = cA[n];
        kC[cb] = cC[n];
    }
    __syncthreads();

    float4v acc[4][8];
#pragma unroll
    for (int hh = 0; hh < 4; hh++)
#pragma unroll
        for (int cb = 0; cb < 8; cb++) acc[hh][cb] = (float4v){0.f, 0.f, 0.f, 0.f};

#pragma unroll
    for (int kk = 0; kk < 4; kk++) {
        int ko = kk * 32 + lg * 8;             // 8 consecutive k per lane
        short8v Ah[4];
#pragma unroll
        for (int hh = 0; hh < 4; hh++)
            Ah[hh] = *(const short8v*)(aggb + (size_t)rc[hh] * HID + ko);
        int chunk = kk * 4 + lg;
#pragma unroll
        for (int cb = 0; cb < 8; cb++) {
            int n = cb * 16 + l15;
            int sidx = n * 128 + ((chunk ^ (n & 7)) << 3);
            short8v bh = *(const short8v*)(Wh + sidx);
            short8v bl = *(const short8v*)(Wl + sidx);
#pragma unroll
            for (int hh = 0; hh < 4; hh++) {
                acc[hh][cb] = __builtin_amdgcn_mfma_f32_16x16x32_bf16(Ah[hh], bh, acc[hh][cb], 0, 0, 0);
                acc[hh][cb] = __builtin_amdgcn_mfma_f32_16x16x32_bf16(Ah[hh], bl, acc[hh][cb], 0, 0, 0);
            }
        }
    }

    // epilogue: two 128-row passes through the LDS tile
#pragma unroll
    for (int p = 0; p < 2; p++) {
        __syncthreads();   // p=0: W reads done; p=1: pass-0 tile reads done
        if ((wid >> 1) == p) {            // waves 2p, 2p+1 own local rows [p*128, p*128+128)
            int lwid = wid & 1;
#pragma unroll
            for (int hh = 0; hh < 4; hh++) {
#pragma unroll
                for (int r = 0; r < 4; r++) {
                    int lr = lwid * 64 + hh * 16 + lg * 4 + r;   // 0..127 within pass tile
                    int swz = ((lr >> 2) & 3) << 2;
#pragma unroll
                    for (int cb = 0; cb < 8; cb++) {
                        int c = cb * 16 + l15;
                        float val = fmaxf(acc[hh][cb][r] * kA[cb] + kC[cb], 0.f);
                        if (POOL && (nbase + p * 128 + lr) >= N) val = 0.f;
                        At[lr * 128 + (c ^ swz)] = val;
                    }
                }
            }
        }
        __syncthreads();
        int tbase = nbase + p * 128;
        if (!POOL) {
            // coalesced bf16 row writes: 16 threads x 8ch cover a 256B row
            int c8 = tid & 15;
            int rb = tid >> 4;
#pragma unroll
            for (int i = 0; i < 8; i++) {
                int r = rb + i * 16;
                int gr = tbase + r;
                if (gr < N) {
                    int swz = ((r >> 2) & 3) << 2;
                    float4 va = *(float4*)&At[r * 128 + ((c8 * 8) ^ swz)];
                    float4 vb = *(float4*)&At[r * 128 + ((c8 * 8 + 4) ^ swz)];
                    ushort8v o;
                    o[0] = f2bf_rne(va.x); o[1] = f2bf_rne(va.y);
                    o[2] = f2bf_rne(va.z); o[3] = f2bf_rne(va.w);
                    o[4] = f2bf_rne(vb.x); o[5] = f2bf_rne(vb.y);
                    o[6] = f2bf_rne(vb.z); o[7] = f2bf_rne(vb.w);
                    *(ushort8v*)&out_h[(size_t)gr * HID + c8 * 8] = o;
                }
            }
        } else {
            // segmented pool reduction: batch is sorted, few segments per tile
            int c  = tid & 127;
            int rh = tid >> 7;          // 0..1, rows rh*64 .. rh*64+63
            int r0 = rh * 64;
            int cg = batch[min(tbase + r0, N - 1)];
            float racc = 0.f;
            for (int r = r0; r < r0 + 64; r++) {
                int gr = min(tbase + r, N - 1);
                int g = batch[gr];
                float vv = At[r * 128 + (c ^ (((r >> 2) & 3) << 2))];
                if (g != cg) {
                    atomicAdd(&out_pool[(size_t)cg * HID + c], racc);
                    racc = 0.f;
                    cg = g;
                }
                racc += vv;
            }
            atomicAdd(&out_pool[(size_t)cg * HID + c], racc);
        }
    }
}

// ---------------- pooling finalize: poolbuf / count -> d_out (writes every element) ----------------

__global__ void finalize_kernel(const float* __restrict__ poolbuf, float* __restrict__ out,
                                const int* __restrict__ gcnt, int total) {
    int i = blockIdx.x * blockDim.x + threadIdx.x;
    if (i < total) {
        int gidx = i >> 7;
        out[i] = poolbuf[i] / fmaxf((float)gcnt[gidx], 1.f);
    }
}

// ---------------- launch ----------------

extern "C" void kernel_launch(void* const* d_in, const int* in_sizes, int n_in,
                              void* d_out, int out_size, void* d_ws, size_t ws_size,
                              hipStream_t stream) {
    const float* x   = (const float*)d_in[0];
    const int*  ei   = (const int*)d_in[1];
    const int*  batch= (const int*)d_in[3];
    const float* W1  = (const float*)d_in[4];
    const float* b1  = (const float*)d_in[5];
    const float* W2  = (const float*)d_in[6];
    const float* b2  = (const float*)d_in[7];
    const float* W3  = (const float*)d_in[8];
    const float* b3  = (const float*)d_in[9];
    const float* g1  = (const float*)d_in[10];
    const float* be1 = (const float*)d_in[11];
    const float* m1  = (const float*)d_in[12];
    const float* v1  = (const float*)d_in[13];
    const float* g2  = (const float*)d_in[14];
    const float* be2 = (const float*)d_in[15];
    const float* m2  = (const float*)d_in[16];
    const float* v2  = (const float*)d_in[17];
    const float* g3  = (const float*)d_in[18];
    const float* be3 = (const float*)d_in[19];
    const float* m3  = (const float*)d_in[20];
    const float* v3  = (const float*)d_in[21];

    const int N  = in_sizes[0] / 6;
    const int E  = in_sizes[1] / 2;
    const int NG = out_size / HID;
    const int* row = ei;
    const int* col = ei + E;
    const int NBKT = (N + 255) >> BSH;        // 391 for N=100000 (<=512 supported)

    char* wp = (char*)d_ws;
    auto alloc = [&](size_t bytes) -> void* {
        void* p = (void*)wp;
        wp += (bytes + 255) & ~(size_t)255;
        return p;
    };
    // bkthist, gcnt, poolbuf adjacent -> single zero span handled by prep_kernel
    int*   bkthist = (int*)alloc((size_t)(NBKT + 1) * 4);
    int*   gcnt    = (int*)alloc((size_t)NG * 4);
    float* poolbuf = (float*)alloc((size_t)NG * HID * 4);
    const int zints = (int)(((char*)poolbuf + (size_t)NG * HID * 4 - (char*)bkthist) / 4);
    float* dinv    = (float*)alloc((size_t)N * 4);
    int*   colptr  = (int*)alloc(((size_t)N + 1) * 4);
    int*   bktbase = (int*)alloc((size_t)(NBKT + 1) * 4);
    int*   bktcur  = (int*)alloc((size_t)(NBKT + 1) * 4);
    int*   chunkhist = (int*)alloc((size_t)256 * 512 * 4);
    uint_t* epart  = (uint_t*)alloc((size_t)E * 4);
    int2*  swsrcs  = (int2*)alloc((size_t)E * 8);
    ushort_t* aggb = (ushort_t*)alloc((size_t)N * HID * 2);
    ushort_t* h    = (ushort_t*)alloc((size_t)N * HID * 2);
    ushort_t* Wsw2 = (ushort_t*)alloc((size_t)2 * HID * HID * 2);
    ushort_t* Wsw3 = (ushort_t*)alloc((size_t)2 * HID * HID * 2);
    float* cA1 = (float*)alloc(HID * 4);
    float* cC1 = (float*)alloc(HID * 4);
    float* cA2 = (float*)alloc(HID * 4);
    float* cC2 = (float*)alloc(HID * 4);
    float* cA3 = (float*)alloc(HID * 4);
    float* cC3 = (float*)alloc(HID * 4);
    float* outf   = (float*)d_out;

    const int B = 256;
    const int ZB = (zints + 255) / 256;
    prep_kernel<<<129 + ZB, B, 0, stream>>>(W2, W3, Wsw2, Wsw3,
                                            b1, g1, be1, m1, v1, cA1, cC1,
                                            b2, g2, be2, m2, v2, cA2, cC2,
                                            b3, g3, be3, m3, v3, cA3, cC3,
                                            bkthist, zints);

    // bucketed CSR build
    const int PB = 256;
    const int pchunk = (E + PB - 1) / PB;
    hist_kernel<<<PB, B, 0, stream>>>(col, E, pchunk, bkthist, chunkhist, NBKT);
    bktscan_kernel<<<1, 512, 0, stream>>>(bkthist, bktbase, bktcur, NBKT);
    part_kernel<<<PB, B, 0, stream>>>(row, col, chunkhist, bktcur, epart, E, pchunk, NBKT);
    count_kernel<<<NBKT, B, 0, stream>>>(epart, bktbase, colptr, dinv, batch, gcnt, N);
    place_kernel<<<NBKT, B, 0, stream>>>(epart, bktbase, colptr, dinv, swsrcs);

    // layer 1 (fused aggregate-x + GEMM1 + BN + ReLU)
    layer1_kernel<<<(N + 31) / 32, B, 0, stream>>>(x, dinv, colptr, swsrcs,
                                                   W1, cA1, cC1, h, N);

    const int NBLK = (N + 255) / 256;
    // layer 2
    agg_kernel<<<(N + 3) / 4, B, 0, stream>>>(h, dinv, colptr, swsrcs, aggb, N);
    gemm_mfma_kernel<false><<<NBLK, 256, 0, stream>>>(aggb, Wsw2, cA2, cC2, h, nullptr, nullptr, N);

    // layer 3 (+ fused mean-pool accumulate into poolbuf)
    agg_kernel<<<(N + 3) / 4, B, 0, stream>>>(h, dinv, colptr, swsrcs, aggb, N);
    gemm_mfma_kernel<true><<<NBLK, 256, 0, stream>>>(aggb, Wsw3, cA3, cC3, nullptr, poolbuf, batch, N);

    finalize_kernel<<<(NG * HID + B - 1) / B, B, 0, stream>>>(poolbuf, outf, gcnt, NG * HID);
}